// Round 17
// baseline (53.530 us; speedup 1.0000x reference)
//
#include <hip/hip_runtime.h>
#include <hip/hip_bf16.h>

// Sliding-window block-causal attention — shared staging + split-window waves.
// B=2 H=8 S=4096 D=64, BLK=32, W=16. f32 I/O, bf16 MFMA, f32 softmax.
// WG = 256 thr = 4 waves = 2 q-blocks x 2 half-windows (v11 mapping).
// K/V union window (17 blocks) staged cooperatively, double-buffered,
// issue-early / write-late, 1 barrier/block (v14 loop). 2-way flash-merge
// (v11) with LDS unioned against the staging buffers. 1024 WGs -> 4 WG/CU.

#define NH    8
#define SEQ   4096
#define DIM   64
#define NBLK  128
#define WIN   16
#define QG    2
#define GROUPS (NBLK / QG)   // 64

typedef __bf16 bf16x8 __attribute__((ext_vector_type(8)));
typedef __bf16 bf16x4 __attribute__((ext_vector_type(4)));
typedef float  f32x4  __attribute__((ext_vector_type(4)));
typedef unsigned short u16;
typedef unsigned int   u32;

#define KSTR 72   // Kt row stride (u16): 144B rows, 16B-aligned
#define VSTR 40   // Vt row stride (u16): 80B rows, 8B-aligned
#define DTHR 8.0f

__device__ __forceinline__ bf16x8 cvt8(f32x4 a, f32x4 b) {
    bf16x8 r;
#pragma unroll
    for (int j = 0; j < 4; ++j) { r[j] = (__bf16)a[j]; r[4 + j] = (__bf16)b[j]; }
    return r;
}

__global__ __launch_bounds__(256)
void sparse_attn_v16(const float* __restrict__ Q,
                     const float* __restrict__ K,
                     const float* __restrict__ V,
                     float* __restrict__ O)
{
    // XCD-chunked bijective swizzle (1024 WGs % 8 == 0)
    const int b  = (int)blockIdx.x;
    const int lg = (b & 7) * 128 + (b >> 3);
    const int bh = lg >> 6;              // 0..15
    const int n0 = (lg & 63) * QG;       // group's first q-block

    const int t    = (int)threadIdx.x;
    const int wave = t >> 6;             // 0..3
    const int lane = t & 63;
    const int l15  = lane & 15;
    const int l4   = lane >> 4;          // 0..3
    const int qi   = wave >> 1;          // q-block within group: 0..1
    const int half = wave & 1;           // window half
    const int nq   = n0 + qi;

    // ---- LDS union: staging (19456 B, loop) aliases merge bufs (18432 B, end)
    __shared__ __align__(16) char smem[19712];
    u16 (*Kt)[32][KSTR]   = (u16 (*)[32][KSTR])smem;            // [2][32][72]
    u16 (*Vt)[64][VSTR]   = (u16 (*)[64][VSTR])(smem + 9216);   // [2][64][40]
    float (*accsh)[32][64] = (float (*)[32][64])smem;           // [QG][32][64]
    float (*mlsh)[4][64]   = (float (*)[4][64])(smem + 16384);  // [QG][4][64]

    const size_t base = (size_t)bh * SEQ * DIM;
    const float SC = 0.125f * 1.44269504088896340736f;  // d^-0.5 * log2(e)

    // staging coords (v14-verified)
    const int skrow = t >> 3;            // K row 0..31
    const int skc   = (t & 7) * 8;       // K d-chunk
    const int svkey = (t & 15) * 2;      // V key pair
    const int svdg  = t >> 4;            // V d-group 0..15

    // ---- Q fragments, pre-scaled (verified v11) ----
    bf16x8 qf[2][2];
#pragma unroll
    for (int rt = 0; rt < 2; ++rt) {
        const float* qp = Q + base + (size_t)(nq * 32 + rt * 16 + l15) * DIM + l4 * 8;
        f32x4 a0 = *(const f32x4*)qp        * SC;
        f32x4 b0 = *(const f32x4*)(qp + 4)  * SC;
        f32x4 a1 = *(const f32x4*)(qp + 32) * SC;
        f32x4 b1 = *(const f32x4*)(qp + 36) * SC;
        qf[rt][0] = cvt8(a0, b0);
        qf[rt][1] = cvt8(a1, b1);
    }

    f32x4 acc[2][4] = {};
    float m[2]  = {-1e30f, -1e30f};
    float lp[2] = {0.f, 0.f};

    // this wave's half-window (verified v11)
    const int kbs = (nq >= WIN - 1) ? nq - (WIN - 1) : 0;
    const int lo  = half ? ((nq - 7 > kbs) ? nq - 7 : kbs) : kbs;
    const int hi  = half ? nq : nq - 8;

    // union window staged by the WG
    const int kb0 = (n0 >= WIN - 1) ? n0 - (WIN - 1) : 0;
    const int kb1 = n0 + QG - 1;

    // ---- prologue: load + stage first block into buf 0 (v14) ----
    f32x4 kra, krb, vra, vrb;
    {
        const float* kp = K + base + (size_t)(kb0 * 32 + skrow) * DIM + skc;
        kra = *(const f32x4*)kp;  krb = *(const f32x4*)(kp + 4);
        const float* vp = V + base + (size_t)(kb0 * 32 + svkey) * DIM + svdg * 4;
        vra = *(const f32x4*)vp;  vrb = *(const f32x4*)(vp + DIM);
    }
    {
        *(bf16x8*)&Kt[0][skrow][skc] = cvt8(kra, krb);
#pragma unroll
        for (int j = 0; j < 4; ++j) {
            u32 w = (u32)__builtin_bit_cast(u16, (__bf16)vra[j])
                  | ((u32)__builtin_bit_cast(u16, (__bf16)vrb[j]) << 16);
            *(u32*)&Vt[0][svdg * 4 + j][svkey] = w;
        }
    }
    __syncthreads();

    int cur = 0;
    for (int kb = kb0; kb <= kb1; ++kb) {
        const bool haveNext = (kb < kb1);

        // ---- issue next block's global loads EARLY (v14) ----
        if (haveNext) {
            const float* kp = K + base + (size_t)((kb + 1) * 32 + skrow) * DIM + skc;
            kra = *(const f32x4*)kp;  krb = *(const f32x4*)(kp + 4);
            const float* vp = V + base + (size_t)((kb + 1) * 32 + svkey) * DIM + svdg * 4;
            vra = *(const f32x4*)vp;  vrb = *(const f32x4*)(vp + DIM);
        }

        if (kb >= lo && kb <= hi) {   // wave-uniform participation
            // ---- fragments from LDS (v14-verified layouts) ----
            bf16x8 kf[2][2];
#pragma unroll
            for (int kh = 0; kh < 2; ++kh)
#pragma unroll
                for (int c = 0; c < 2; ++c)
                    kf[kh][c] = *(const bf16x8*)&Kt[cur][kh * 16 + l15][c * 32 + l4 * 8];

            bf16x8 vf[4];
#pragma unroll
            for (int dt = 0; dt < 4; ++dt) {
                bf16x4 vlo = *(const bf16x4*)&Vt[cur][dt * 16 + l15][l4 * 4];
                bf16x4 vhi = *(const bf16x4*)&Vt[cur][dt * 16 + l15][16 + l4 * 4];
#pragma unroll
                for (int j = 0; j < 4; ++j) { vf[dt][j] = vlo[j]; vf[dt][4 + j] = vhi[j]; }
            }

            // ---- swapped QK^T (verified) ----
            f32x4 s[2][2];
#pragma unroll
            for (int rt = 0; rt < 2; ++rt)
#pragma unroll
                for (int kh = 0; kh < 2; ++kh) {
                    f32x4 a = {};
                    a = __builtin_amdgcn_mfma_f32_16x16x32_bf16(kf[kh][0], qf[rt][0], a, 0, 0, 0);
                    a = __builtin_amdgcn_mfma_f32_16x16x32_bf16(kf[kh][1], qf[rt][1], a, 0, 0, 0);
                    s[rt][kh] = a;
                }

            // ---- causal mask (verified) ----
            if (kb == nq) {
#pragma unroll
                for (int rt = 0; rt < 2; ++rt)
#pragma unroll
                    for (int kh = 0; kh < 2; ++kh)
#pragma unroll
                        for (int r = 0; r < 4; ++r)
                            if (kh * 16 + l4 * 4 + r > rt * 16 + l15)
                                s[rt][kh][r] = -1e30f;
            }

            // ---- defer-max (verified) ----
            bool ok = true;
#pragma unroll
            for (int rt = 0; rt < 2; ++rt)
#pragma unroll
                for (int kh = 0; kh < 2; ++kh)
#pragma unroll
                    for (int r = 0; r < 4; ++r)
                        ok &= (s[rt][kh][r] <= m[rt] + DTHR);

            if (!__all(ok)) {
#pragma unroll
                for (int rt = 0; rt < 2; ++rt) {
                    float t0 = -1e30f;
#pragma unroll
                    for (int kh = 0; kh < 2; ++kh)
#pragma unroll
                        for (int r = 0; r < 4; ++r) t0 = fmaxf(t0, s[rt][kh][r]);
                    t0 = fmaxf(t0, __shfl_xor(t0, 16));
                    t0 = fmaxf(t0, __shfl_xor(t0, 32));
                    const float mn = fmaxf(m[rt], t0);
                    const float al = exp2f(m[rt] - mn);
                    m[rt] = mn;
                    lp[rt] *= al;
#pragma unroll
                    for (int dt = 0; dt < 4; ++dt)
#pragma unroll
                        for (int r = 0; r < 4; ++r) acc[rt][dt][r] *= al;
                }
            }

            // ---- exp2 + pack P (verified) ----
            bf16x8 pbf[2];
#pragma unroll
            for (int rt = 0; rt < 2; ++rt) {
                float psum = 0.f;
#pragma unroll
                for (int j = 0; j < 8; ++j) {
                    const float pv = exp2f(s[rt][j >> 2][j & 3] - m[rt]);
                    psum += pv;
                    pbf[rt][j] = (__bf16)pv;
                }
                lp[rt] += psum;
            }

            // ---- PV (verified) ----
#pragma unroll
            for (int rt = 0; rt < 2; ++rt)
#pragma unroll
                for (int dt = 0; dt < 4; ++dt)
                    acc[rt][dt] = __builtin_amdgcn_mfma_f32_16x16x32_bf16(
                        vf[dt], pbf[rt], acc[rt][dt], 0, 0, 0);
        }

        // ---- write-late: stage kb+1 into the other buffer (v14) ----
        if (haveNext) {
            *(bf16x8*)&Kt[cur ^ 1][skrow][skc] = cvt8(kra, krb);
#pragma unroll
            for (int j = 0; j < 4; ++j) {
                u32 w = (u32)__builtin_bit_cast(u16, (__bf16)vra[j])
                      | ((u32)__builtin_bit_cast(u16, (__bf16)vrb[j]) << 16);
                *(u32*)&Vt[cur ^ 1][svdg * 4 + j][svkey] = w;
            }
        }

        __syncthreads();
        cur ^= 1;
    }

    // ---- final l reduction (verified) ----
    float l[2];
#pragma unroll
    for (int rt = 0; rt < 2; ++rt) {
        float ps = lp[rt];
        ps += __shfl_xor(ps, 16);
        ps += __shfl_xor(ps, 32);
        l[rt] = ps;
    }

    // ---- 2-way flash-merge (verified v11; LDS aliases staging, ordered by
    //      the loop's final __syncthreads) ----
    if (half == 1) {
#pragma unroll
        for (int rt = 0; rt < 2; ++rt) {
            mlsh[qi][rt][lane]     = m[rt];
            mlsh[qi][2 + rt][lane] = l[rt];
#pragma unroll
            for (int dt = 0; dt < 4; ++dt)
#pragma unroll
                for (int r = 0; r < 4; ++r)
                    accsh[qi][rt * 16 + dt * 4 + r][lane] = acc[rt][dt][r];
        }
    }

    __syncthreads();

    if (half == 0) {
#pragma unroll
        for (int rt = 0; rt < 2; ++rt) {
            const float m2 = mlsh[qi][rt][lane];
            const float l2 = mlsh[qi][2 + rt][lane];
            const float mn = fmaxf(m[rt], m2);
            const float a1 = exp2f(m[rt] - mn);
            const float a2 = exp2f(m2 - mn);
            const float inv = 1.0f / (l[rt] * a1 + l2 * a2);
            float* op = O + base + (size_t)(nq * 32 + rt * 16 + l15) * DIM + l4 * 4;
#pragma unroll
            for (int dt = 0; dt < 4; ++dt) {
                f32x4 v;
#pragma unroll
                for (int r = 0; r < 4; ++r)
                    v[r] = (acc[rt][dt][r] * a1 +
                            accsh[qi][rt * 16 + dt * 4 + r][lane] * a2) * inv;
                *(f32x4*)(op + dt * 16) = v;
            }
        }
    }
}

extern "C" void kernel_launch(void* const* d_in, const int* in_sizes, int n_in,
                              void* d_out, int out_size, void* d_ws, size_t ws_size,
                              hipStream_t stream)
{
    const float* Q = (const float*)d_in[0];
    const float* K = (const float*)d_in[1];
    const float* V = (const float*)d_in[2];
    float*       O = (float*)d_out;

    const int nwg = 2 * NH * GROUPS;   // 1024 WGs x 256 thr
    hipLaunchKernelGGL(sparse_attn_v16, dim3(nwg), dim3(256), 0, stream,
                       Q, K, V, O);
}

// Round 18
// 36.925 us; speedup vs baseline: 1.4497x; 1.4497x over previous
//
#include <hip/hip_runtime.h>
#include <hip/hip_bf16.h>

// Sliding-window block-causal attention — small barrier groups, full windows.
// B=2 H=8 S=4096 D=64, BLK=32, W=16. f32 I/O, bf16 MFMA, f32 softmax.
// WG = 128 thr = 2 waves; wave w owns q-block n0+w with its FULL 16-block
// window (participation 16/17, no merge). K/V union window staged
// cooperatively, double-buffered, issue-early/write-late, 1 barrier/block
// (v14-verified loop). 1024 WGs -> 4 barrier-groups/CU, 8 waves/CU.

#define NH    8
#define SEQ   4096
#define DIM   64
#define NBLK  128
#define WIN   16
#define QG    2
#define GROUPS (NBLK / QG)   // 64

typedef __bf16 bf16x8 __attribute__((ext_vector_type(8)));
typedef __bf16 bf16x4 __attribute__((ext_vector_type(4)));
typedef float  f32x4  __attribute__((ext_vector_type(4)));
typedef unsigned short u16;
typedef unsigned int   u32;

#define KSTR 72   // Kt row stride (u16): 144B rows, 16B-aligned
#define VSTR 40   // Vt row stride (u16): 80B rows, 8B-aligned
#define DTHR 8.0f

__device__ __forceinline__ bf16x8 cvt8(f32x4 a, f32x4 b) {
    bf16x8 r;
#pragma unroll
    for (int j = 0; j < 4; ++j) { r[j] = (__bf16)a[j]; r[4 + j] = (__bf16)b[j]; }
    return r;
}

__global__ __launch_bounds__(128)
void sparse_attn_v17(const float* __restrict__ Q,
                     const float* __restrict__ K,
                     const float* __restrict__ V,
                     float* __restrict__ O)
{
    // XCD-chunked bijective swizzle (1024 WGs % 8 == 0)
    const int b  = (int)blockIdx.x;
    const int lg = (b & 7) * 128 + (b >> 3);
    const int bh = lg >> 6;              // 0..15
    const int n0 = (lg & 63) * QG;       // group's first q-block

    const int t    = (int)threadIdx.x;   // 0..127
    const int wave = t >> 6;             // 0..1, owns q-block n0+wave
    const int lane = t & 63;
    const int l15  = lane & 15;
    const int l4   = lane >> 4;          // 0..3
    const int nq   = n0 + wave;

    __shared__ u16 Kt[2][32][KSTR];      // 9.2 KB
    __shared__ u16 Vt[2][64][VSTR];      // 10.2 KB

    const size_t base = (size_t)bh * SEQ * DIM;
    const float SC = 0.125f * 1.44269504088896340736f;  // d^-0.5 * log2(e)

    // ---- staging coords (128 threads stage one 32x64 block of K and V) ----
    const int krow = t >> 2;             // K row 0..31
    const int kc4  = (t & 3) * 16;       // K d-chunk start (16 d's per thread)
    const int vkey = (t & 15) * 2;       // V key pair
    const int vdg  = t >> 4;             // V d-group 0..7 (8 d's per thread)

    // ---- Q fragments, pre-scaled (verified v11) ----
    bf16x8 qf[2][2];
#pragma unroll
    for (int rt = 0; rt < 2; ++rt) {
        const float* qp = Q + base + (size_t)(nq * 32 + rt * 16 + l15) * DIM + l4 * 8;
        f32x4 a0 = *(const f32x4*)qp        * SC;
        f32x4 b0 = *(const f32x4*)(qp + 4)  * SC;
        f32x4 a1 = *(const f32x4*)(qp + 32) * SC;
        f32x4 b1 = *(const f32x4*)(qp + 36) * SC;
        qf[rt][0] = cvt8(a0, b0);
        qf[rt][1] = cvt8(a1, b1);
    }

    f32x4 acc[2][4] = {};
    float m[2]  = {-1e30f, -1e30f};
    float lp[2] = {0.f, 0.f};

    const int lo  = (nq >= WIN - 1) ? nq - (WIN - 1) : 0;   // this wave's window
    const int kb0 = (n0 >= WIN - 1) ? n0 - (WIN - 1) : 0;   // union start
    const int kb1 = n0 + QG - 1;                             // union end

    // ---- prologue: load + stage first block into buf 0 ----
    f32x4 kr0, kr1, kr2, kr3, va0, va1, vb0, vb1;
    {
        const float* kp = K + base + (size_t)(kb0 * 32 + krow) * DIM + kc4;
        kr0 = *(const f32x4*)kp;      kr1 = *(const f32x4*)(kp + 4);
        kr2 = *(const f32x4*)(kp + 8); kr3 = *(const f32x4*)(kp + 12);
        const float* vp = V + base + (size_t)(kb0 * 32 + vkey) * DIM + vdg * 8;
        va0 = *(const f32x4*)vp;        va1 = *(const f32x4*)(vp + 4);
        vb0 = *(const f32x4*)(vp + DIM); vb1 = *(const f32x4*)(vp + DIM + 4);
    }
    {
        *(bf16x8*)&Kt[0][krow][kc4]     = cvt8(kr0, kr1);
        *(bf16x8*)&Kt[0][krow][kc4 + 8] = cvt8(kr2, kr3);
#pragma unroll
        for (int j = 0; j < 4; ++j) {
            u32 w0 = (u32)__builtin_bit_cast(u16, (__bf16)va0[j])
                   | ((u32)__builtin_bit_cast(u16, (__bf16)vb0[j]) << 16);
            *(u32*)&Vt[0][vdg * 8 + j][vkey] = w0;
            u32 w1 = (u32)__builtin_bit_cast(u16, (__bf16)va1[j])
                   | ((u32)__builtin_bit_cast(u16, (__bf16)vb1[j]) << 16);
            *(u32*)&Vt[0][vdg * 8 + 4 + j][vkey] = w1;
        }
    }
    __syncthreads();

    int cur = 0;
    for (int kb = kb0; kb <= kb1; ++kb) {
        const bool haveNext = (kb < kb1);

        // ---- issue next block's global loads EARLY (hidden under compute) ----
        if (haveNext) {
            const float* kp = K + base + (size_t)((kb + 1) * 32 + krow) * DIM + kc4;
            kr0 = *(const f32x4*)kp;       kr1 = *(const f32x4*)(kp + 4);
            kr2 = *(const f32x4*)(kp + 8); kr3 = *(const f32x4*)(kp + 12);
            const float* vp = V + base + (size_t)((kb + 1) * 32 + vkey) * DIM + vdg * 8;
            va0 = *(const f32x4*)vp;         va1 = *(const f32x4*)(vp + 4);
            vb0 = *(const f32x4*)(vp + DIM); vb1 = *(const f32x4*)(vp + DIM + 4);
        }

        if (kb >= lo && kb <= nq) {   // wave-uniform participation (16 of 17)
            // ---- fragments from LDS (v14-verified layouts) ----
            bf16x8 kf[2][2];
#pragma unroll
            for (int kh = 0; kh < 2; ++kh)
#pragma unroll
                for (int c = 0; c < 2; ++c)
                    kf[kh][c] = *(const bf16x8*)&Kt[cur][kh * 16 + l15][c * 32 + l4 * 8];

            bf16x8 vf[4];
#pragma unroll
            for (int dt = 0; dt < 4; ++dt) {
                bf16x4 vlo = *(const bf16x4*)&Vt[cur][dt * 16 + l15][l4 * 4];
                bf16x4 vhi = *(const bf16x4*)&Vt[cur][dt * 16 + l15][16 + l4 * 4];
#pragma unroll
                for (int j = 0; j < 4; ++j) { vf[dt][j] = vlo[j]; vf[dt][4 + j] = vhi[j]; }
            }

            // ---- swapped QK^T (verified) ----
            f32x4 s[2][2];
#pragma unroll
            for (int rt = 0; rt < 2; ++rt)
#pragma unroll
                for (int kh = 0; kh < 2; ++kh) {
                    f32x4 a = {};
                    a = __builtin_amdgcn_mfma_f32_16x16x32_bf16(kf[kh][0], qf[rt][0], a, 0, 0, 0);
                    a = __builtin_amdgcn_mfma_f32_16x16x32_bf16(kf[kh][1], qf[rt][1], a, 0, 0, 0);
                    s[rt][kh] = a;
                }

            // ---- causal mask (diagonal only, verified) ----
            if (kb == nq) {
#pragma unroll
                for (int rt = 0; rt < 2; ++rt)
#pragma unroll
                    for (int kh = 0; kh < 2; ++kh)
#pragma unroll
                        for (int r = 0; r < 4; ++r)
                            if (kh * 16 + l4 * 4 + r > rt * 16 + l15)
                                s[rt][kh][r] = -1e30f;
            }

            // ---- defer-max (verified) ----
            bool ok = true;
#pragma unroll
            for (int rt = 0; rt < 2; ++rt)
#pragma unroll
                for (int kh = 0; kh < 2; ++kh)
#pragma unroll
                    for (int r = 0; r < 4; ++r)
                        ok &= (s[rt][kh][r] <= m[rt] + DTHR);

            if (!__all(ok)) {
#pragma unroll
                for (int rt = 0; rt < 2; ++rt) {
                    float t0 = -1e30f;
#pragma unroll
                    for (int kh = 0; kh < 2; ++kh)
#pragma unroll
                        for (int r = 0; r < 4; ++r) t0 = fmaxf(t0, s[rt][kh][r]);
                    t0 = fmaxf(t0, __shfl_xor(t0, 16));
                    t0 = fmaxf(t0, __shfl_xor(t0, 32));
                    const float mn = fmaxf(m[rt], t0);
                    const float al = exp2f(m[rt] - mn);
                    m[rt] = mn;
                    lp[rt] *= al;
#pragma unroll
                    for (int dt = 0; dt < 4; ++dt)
#pragma unroll
                        for (int r = 0; r < 4; ++r) acc[rt][dt][r] *= al;
                }
            }

            // ---- exp2 + pack P (verified) ----
            bf16x8 pbf[2];
#pragma unroll
            for (int rt = 0; rt < 2; ++rt) {
                float psum = 0.f;
#pragma unroll
                for (int j = 0; j < 8; ++j) {
                    const float pv = exp2f(s[rt][j >> 2][j & 3] - m[rt]);
                    psum += pv;
                    pbf[rt][j] = (__bf16)pv;
                }
                lp[rt] += psum;
            }

            // ---- PV (verified) ----
#pragma unroll
            for (int rt = 0; rt < 2; ++rt)
#pragma unroll
                for (int dt = 0; dt < 4; ++dt)
                    acc[rt][dt] = __builtin_amdgcn_mfma_f32_16x16x32_bf16(
                        vf[dt], pbf[rt], acc[rt][dt], 0, 0, 0);
        }

        // ---- write-late: stage kb+1 into the other buffer ----
        if (haveNext) {
            *(bf16x8*)&Kt[cur ^ 1][krow][kc4]     = cvt8(kr0, kr1);
            *(bf16x8*)&Kt[cur ^ 1][krow][kc4 + 8] = cvt8(kr2, kr3);
#pragma unroll
            for (int j = 0; j < 4; ++j) {
                u32 w0 = (u32)__builtin_bit_cast(u16, (__bf16)va0[j])
                       | ((u32)__builtin_bit_cast(u16, (__bf16)vb0[j]) << 16);
                *(u32*)&Vt[cur ^ 1][vdg * 8 + j][vkey] = w0;
                u32 w1 = (u32)__builtin_bit_cast(u16, (__bf16)va1[j])
                       | ((u32)__builtin_bit_cast(u16, (__bf16)vb1[j]) << 16);
                *(u32*)&Vt[cur ^ 1][vdg * 8 + 4 + j][vkey] = w1;
            }
        }

        __syncthreads();
        cur ^= 1;
    }

    // ---- epilogue (verified v8): reduce l, normalize, vector store ----
#pragma unroll
    for (int rt = 0; rt < 2; ++rt) {
        float ps = lp[rt];
        ps += __shfl_xor(ps, 16);
        ps += __shfl_xor(ps, 32);
        const float inv = 1.0f / ps;
        float* op = O + base + (size_t)(nq * 32 + rt * 16 + l15) * DIM + l4 * 4;
#pragma unroll
        for (int dt = 0; dt < 4; ++dt) {
            f32x4 v;
#pragma unroll
            for (int r = 0; r < 4; ++r) v[r] = acc[rt][dt][r] * inv;
            *(f32x4*)(op + dt * 16) = v;
        }
    }
}

extern "C" void kernel_launch(void* const* d_in, const int* in_sizes, int n_in,
                              void* d_out, int out_size, void* d_ws, size_t ws_size,
                              hipStream_t stream)
{
    const float* Q = (const float*)d_in[0];
    const float* K = (const float*)d_in[1];
    const float* V = (const float*)d_in[2];
    float*       O = (float*)d_out;

    const int nwg = 2 * NH * GROUPS;   // 1024 WGs x 128 thr
    hipLaunchKernelGGL(sparse_attn_v17, dim3(nwg), dim3(128), 0, stream,
                       Q, K, V, O);
}